// Round 5
// baseline (1132.547 us; speedup 1.0000x reference)
//
#include <hip/hip_runtime.h>
#include <stdint.h>
#include <math.h>

// Round 11 (from r10 counters: fold 336us, VALUBusy 25%, conflicts 0, occ 40%,
// 6.5 cyc/entry vs ~2.3 LDS floor => lgkmcnt conflation between s_load pairs
// and ds_read gathers; select inferred ~300us vs 85us floor => atomic/barrier
// radix overhead):
//  - fold: pair stream moved from SMEM to VMEM (opaque-VGPR zero forces
//    per-lane address; 64 same-address lanes coalesce to one L2 request).
//    vmcnt is counted+in-order -> ping-pong 4-entry chunk prefetch survives;
//    ds_read waits become precise (only DS on lgkmcnt). cm8 round-up uses
//    the validated zero-pad no-op (fmaf(+/-0,x,a)==a; a never -0) -> no
//    remainder loop, no register copies.
//  - select: rewritten. One wave per row, 64 keys/lane in VGPRs, 32-step
//    bitwise binary search for the exact k-th-largest monotone key via
//    ballot+popcount (no LDS, no atomics, no barriers). P = max C with
//    count_ge(C) >= k == exact k-th largest key; output keeps key >= P
//    (ties kept) -- identical semantics to the validated radix select.
// Numerics elsewhere unchanged: ascending-k f32 fmaf fold, +bias, *boost,
// monotone u32 key transform.

#define BATCH 16384
#define K_DIM 512
#define N_DIM 4096
#define MAXE 64
#define PSTRIDE 72   // padded pair stride (32B-aligned chunks, prefetch-safe)
#define ROWS_A 64
#define XPAD 65      // xT row stride: conflict-free b32 reads + staging writes

typedef float f32x4 __attribute__((ext_vector_type(4)));
typedef unsigned int u32;
typedef unsigned long long u64;
typedef u64 u64x2 __attribute__((ext_vector_type(2)));

// ---------- boost table ----------
__global__ void boost_kernel(const float* __restrict__ duty,
                             const int* __restrict__ kptr,
                             float* __restrict__ boost) {
  const int j = blockIdx.x * blockDim.x + threadIdx.x;
  if (j < N_DIM) {
    const float td = (float)((double)kptr[0] / (double)N_DIM);
    const float arg = 0.5f * (td - duty[j]);      // f32 ops, as reference
    boost[j] = (float)exp((double)arg);           // correctly-rounded f32 exp
  }
}

// ---------- compress: per-column nonzeros, ascending k ----------
__global__ __launch_bounds__(256) void compress_kernel(
    const float* __restrict__ W, const float* __restrict__ mask,
    unsigned short* __restrict__ cIdx, float* __restrict__ cVal,
    int* __restrict__ cnt) {
  const int j = blockIdx.x * 4 + (threadIdx.x >> 6);  // one wave per column
  const int lane = threadIdx.x & 63;
  if (j >= N_DIM) return;
  const float* mr = mask + (size_t)j * K_DIM;
  const float* wr = W + (size_t)j * K_DIM;
  int base = 0;
#pragma unroll
  for (int c = 0; c < K_DIM / 64; ++c) {
    const int k = c * 64 + lane;
    const bool act = (mr[k] != 0.0f);
    const unsigned long long bal = __ballot(act);
    const int pos = __popcll(bal & ((1ull << lane) - 1ull));
    if (act && base + pos < MAXE) {
      cIdx[(size_t)j * MAXE + base + pos] = (unsigned short)k;
      cVal[(size_t)j * MAXE + base + pos] = wr[k];   // mask==1 -> exact
    }
    base += (int)__popcll(bal);
  }
  if (lane == 0) cnt[j] = base < MAXE ? base : MAXE;
}

// ---------- pack (k*XPAD, w-bits) pairs, zero-padded to PSTRIDE ----------
__global__ __launch_bounds__(256) void fillA_kernel(
    const unsigned short* __restrict__ cIdx, const float* __restrict__ cVal,
    const int* __restrict__ cnt, uint2* __restrict__ pairsA) {
  const int idx = blockIdx.x * 256 + threadIdx.x;  // 0 .. 4096*72-1
  const int j = idx / PSTRIDE;
  const int e = idx - j * PSTRIDE;
  uint2 pr;
  if (e < cnt[j]) {                                // cnt<=MAXE<=PSTRIDE
    pr.x = (u32)cIdx[(size_t)j * MAXE + e] * (u32)XPAD;  // xT element offset
    pr.y = __float_as_uint(cVal[(size_t)j * MAXE + e]);
  } else {
    pr.x = 0u; pr.y = 0u;                          // exact fold no-op
  }
  pairsA[(size_t)j * PSTRIDE + e] = pr;
}

// ---------- fold: 16 waves/tile, VMEM pair stream, ping-pong prefetch ----------
__global__ __launch_bounds__(1024, 1) void fold_kernel(
    const float* __restrict__ x, const uint2* __restrict__ pairsA,
    const int* __restrict__ cnt, float* __restrict__ y) {
  __shared__ float xT[K_DIM * XPAD];          // 512*65*4 = 133,120 B
  const int tid = threadIdx.x;
  const int lane = tid & 63;
  const int wave = __builtin_amdgcn_readfirstlane(tid >> 6);  // 0..15 uniform
  const int row0 = blockIdx.x * ROWS_A;

  u32 vz;                                          // opaque zero: forces VMEM
  asm volatile("v_mov_b32 %0, 0" : "=v"(vz));

  // stage xT[k*XPAD + row] = x[row0+row][k]; coalesced global, LDS 2-way free
#pragma unroll 1
  for (int i = 0; i < (ROWS_A * K_DIM) / 1024; ++i) {  // 32 iters
    const int flat = i * 1024 + tid;
    const int row = flat >> 9;                         // /512
    const int k = flat & (K_DIM - 1);
    xT[k * XPAD + row] = x[(size_t)(row0 + row) * K_DIM + k];
  }
  __syncthreads();

  const int jbase = wave * (N_DIM / 16);               // 256 cols per wave

#pragma unroll 1
  for (int g = 0; g < 8; ++g) {                        // 8 groups of 32 cols
    float acc[32];
#pragma unroll
    for (int q = 0; q < 32; ++q) acc[q] = 0.0f;

#pragma unroll
    for (int c4 = 0; c4 < 8; ++c4) {                   // full unroll: static acc
      const int j0 = jbase + g * 32 + c4 * 4;
      const int4 cn = *(const int4*)(cnt + j0);
      int cmax = cn.x > cn.y ? cn.x : cn.y;
      cmax = cn.z > cmax ? cn.z : cmax;
      cmax = cn.w > cmax ? cn.w : cmax;
      const int cm8 = (cmax + 7) & ~7;                 // pad = exact no-ops
      const u64* q0 = (const u64*)(pairsA + (size_t)(j0 + 0) * PSTRIDE) + vz;
      const u64* q1 = (const u64*)(pairsA + (size_t)(j0 + 1) * PSTRIDE) + vz;
      const u64* q2 = (const u64*)(pairsA + (size_t)(j0 + 2) * PSTRIDE) + vz;
      const u64* q3 = (const u64*)(pairsA + (size_t)(j0 + 3) * PSTRIDE) + vz;
      float a0 = 0.0f, a1 = 0.0f, a2 = 0.0f, a3 = 0.0f;
      u64x2 A0[2], A1[2], A2[2], A3[2];
      A0[0] = *(const u64x2*)(q0);     A0[1] = *(const u64x2*)(q0 + 2);
      A1[0] = *(const u64x2*)(q1);     A1[1] = *(const u64x2*)(q1 + 2);
      A2[0] = *(const u64x2*)(q2);     A2[1] = *(const u64x2*)(q2 + 2);
      A3[0] = *(const u64x2*)(q3);     A3[1] = *(const u64x2*)(q3 + 2);
#pragma unroll 1
      for (int e = 0; e < cm8; e += 8) {               // ping-pong, no copies
        u64x2 B0[2], B1[2], B2[2], B3[2];
        B0[0] = *(const u64x2*)(q0 + e + 4); B0[1] = *(const u64x2*)(q0 + e + 6);
        B1[0] = *(const u64x2*)(q1 + e + 4); B1[1] = *(const u64x2*)(q1 + e + 6);
        B2[0] = *(const u64x2*)(q2 + e + 4); B2[1] = *(const u64x2*)(q2 + e + 6);
        B3[0] = *(const u64x2*)(q3 + e + 4); B3[1] = *(const u64x2*)(q3 + e + 6);
#pragma unroll
        for (int h = 0; h < 2; ++h)
#pragma unroll
          for (int q = 0; q < 2; ++q) {                // entries e..e+3 asc
            const u64 e0 = A0[h][q], e1 = A1[h][q], e2 = A2[h][q], e3 = A3[h][q];
            a0 = fmaf(__uint_as_float((u32)(e0 >> 32)), xT[(u32)e0 + lane], a0);
            a1 = fmaf(__uint_as_float((u32)(e1 >> 32)), xT[(u32)e1 + lane], a1);
            a2 = fmaf(__uint_as_float((u32)(e2 >> 32)), xT[(u32)e2 + lane], a2);
            a3 = fmaf(__uint_as_float((u32)(e3 >> 32)), xT[(u32)e3 + lane], a3);
          }
        A0[0] = *(const u64x2*)(q0 + e + 8); A0[1] = *(const u64x2*)(q0 + e + 10);
        A1[0] = *(const u64x2*)(q1 + e + 8); A1[1] = *(const u64x2*)(q1 + e + 10);
        A2[0] = *(const u64x2*)(q2 + e + 8); A2[1] = *(const u64x2*)(q2 + e + 10);
        A3[0] = *(const u64x2*)(q3 + e + 8); A3[1] = *(const u64x2*)(q3 + e + 10);
#pragma unroll
        for (int h = 0; h < 2; ++h)
#pragma unroll
          for (int q = 0; q < 2; ++q) {                // entries e+4..e+7 asc
            const u64 e0 = B0[h][q], e1 = B1[h][q], e2 = B2[h][q], e3 = B3[h][q];
            a0 = fmaf(__uint_as_float((u32)(e0 >> 32)), xT[(u32)e0 + lane], a0);
            a1 = fmaf(__uint_as_float((u32)(e1 >> 32)), xT[(u32)e1 + lane], a1);
            a2 = fmaf(__uint_as_float((u32)(e2 >> 32)), xT[(u32)e2 + lane], a2);
            a3 = fmaf(__uint_as_float((u32)(e3 >> 32)), xT[(u32)e3 + lane], a3);
          }
      }
      acc[c4 * 4 + 0] = a0;
      acc[c4 * 4 + 1] = a1;
      acc[c4 * 4 + 2] = a2;
      acc[c4 * 4 + 3] = a3;
    }

    // 128B contiguous per lane
    float* yp = y + (size_t)(row0 + lane) * N_DIM + jbase + g * 32;
#pragma unroll
    for (int q = 0; q < 8; ++q)
      *(f32x4*)(yp + q * 4) =
          (f32x4){acc[q * 4], acc[q * 4 + 1], acc[q * 4 + 2], acc[q * 4 + 3]};
  }
}

// ---------- select v3: one wave per row, ballot bit-search, no LDS ----------
__global__ __launch_bounds__(256) void select_kernel(
    const float* __restrict__ bvec, const float* __restrict__ boost,
    const int* __restrict__ kptr, float* __restrict__ out) {
  const int lane = threadIdx.x & 63;
  const int row = blockIdx.x * 4 + (threadIdx.x >> 6);
  const u32 kk = (u32)kptr[0];
  float* orow = out + (size_t)row * N_DIM;

  float yv[64];
  u32 kv[64];
#pragma unroll
  for (int v = 0; v < 16; ++v) {
    const int j = v * 256 + lane * 4;                 // f32x4, coalesced
    const f32x4 a = *(const f32x4*)(orow + j);
    const f32x4 b = *(const f32x4*)(bvec + j);
    const f32x4 c = *(const f32x4*)(boost + j);
#pragma unroll
    for (int q = 0; q < 4; ++q) {
      const float yy = a[q] + b[q];                   // single f32 add
      const float t = yy * c[q];                      // single f32 mult
      const u32 u = __float_as_uint(t);
      yv[v * 4 + q] = yy;
      kv[v * 4 + q] = (u & 0x80000000u) ? ~u : (u | 0x80000000u);
    }
  }

  // exact k-th-largest key via 32-bit greedy search:
  // P = max C s.t. count(key >= C) >= k  ==  key of k-th largest (ties >=)
  u32 P = 0u;
#pragma unroll 1
  for (int bit = 31; bit >= 0; --bit) {
    const u32 C = P | (1u << bit);
    u32 c = 0u;
#pragma unroll
    for (int s = 0; s < 64; ++s)
      c += (u32)__popcll(__ballot(kv[s] >= C));       // v_cmp + s_bcnt1
    if (c >= kk) P = C;                               // uniform
  }

#pragma unroll
  for (int v = 0; v < 16; ++v) {
    const int j = v * 256 + lane * 4;
    f32x4 o;
#pragma unroll
    for (int q = 0; q < 4; ++q)
      o[q] = (kv[v * 4 + q] >= P) ? yv[v * 4 + q] : 0.0f;
    *(f32x4*)(orow + j) = o;
  }
}

extern "C" void kernel_launch(void* const* d_in, const int* in_sizes, int n_in,
                              void* d_out, int out_size, void* d_ws, size_t ws_size,
                              hipStream_t stream) {
  const float* x     = (const float*)d_in[0];
  const float* W     = (const float*)d_in[1];
  const float* bvec  = (const float*)d_in[2];
  const float* wmask = (const float*)d_in[3];
  const float* duty  = (const float*)d_in[4];
  const int* kptr    = (const int*)d_in[5];
  float* out = (float*)d_out;

  uint8_t* ws = (uint8_t*)d_ws;
  unsigned short* cIdx = (unsigned short*)(ws);                 // 512 KiB
  float* cVal          = (float*)(ws + (1u << 20));             // 1 MiB
  int* cnt             = (int*)(ws + (2u << 20));               // 16 KiB
  float* boost         = (float*)(ws + (2u << 20) + (64u << 10));
  uint2* pairsA        = (uint2*)(ws + (3u << 20));             // 2.36 MiB

  boost_kernel<<<16, 256, 0, stream>>>(duty, kptr, boost);
  compress_kernel<<<N_DIM / 4, 256, 0, stream>>>(W, wmask, cIdx, cVal, cnt);
  fillA_kernel<<<(N_DIM * PSTRIDE) / 256, 256, 0, stream>>>(cIdx, cVal, cnt,
                                                            pairsA);
  fold_kernel<<<BATCH / ROWS_A, 1024, 0, stream>>>(x, pairsA, cnt, out);
  select_kernel<<<BATCH / 4, 256, 0, stream>>>(bvec, boost, kptr, out);
}

// Round 6
// 1124.189 us; speedup vs baseline: 1.0074x; 1.0074x over previous
//
#include <hip/hip_runtime.h>
#include <stdint.h>
#include <math.h>

// Round 12.
// r11 post-mortem: VMEM pair stream REGRESSED fold 336->628 (theory wrong);
// select v3 inferred ~450-470us (yv[64]+kv[64] => ~150 VGPR, spills).
// This round:
//  - fold v3: lane=COLUMN. Per entry: LDS base = per-lane VGPR (k*260 baked
//    in pairT), 64 batch rows via ds_read_b32 imm offsets -> 2 instr/gather,
//    no addr math, no scalar loads in chain, 64 indep fma chains.
//    nnz counting-sort (r6 machinery) groups similar-count columns per wave
//    -> per-wave-max padding ~1.05x. Random-k banks ~5-way max (~1.7x tax,
//    m136) - accepted, measured via SQ_LDS_BANK_CONFLICT.
//  - fold writes y in SORTED column order (coalesced 256B/instr); select
//    operates in sorted space (top-k set-invariant; bias/boost pre-permuted)
//    and un-permutes at the final scattered store (L2 combines: 64KB
//    dirty/block).
//  - select v4: one wave/row; kv[64] only (~90 VGPR, no spills); pristine y
//    parked in LDS (64KB/block) to avoid in-place RAW hazard; validated
//    ballot bit-search threshold; yy/key recomputed bit-identically at write.
// Numerics unchanged: ascending-k f32 fmaf fold from +0 (zero-pad exact
// no-op, acc never -0), +bias, *boost, monotone-u32 key, ties >=.

#define BATCH 16384
#define K_DIM 512
#define N_DIM 4096
#define MAXE 64
#define ROWS_A 64
#define XPAD 65   // xT k-stride in floats; bank(k,r) = (k+r)%32

typedef float f32x4 __attribute__((ext_vector_type(4)));
typedef unsigned int u32;

// ---------- boost table ----------
__global__ void boost_kernel(const float* __restrict__ duty,
                             const int* __restrict__ kptr,
                             float* __restrict__ boost) {
  const int j = blockIdx.x * blockDim.x + threadIdx.x;
  if (j < N_DIM) {
    const float td = (float)((double)kptr[0] / (double)N_DIM);
    const float arg = 0.5f * (td - duty[j]);      // f32 ops, as reference
    boost[j] = (float)exp((double)arg);           // correctly-rounded f32 exp
  }
}

// ---------- compress: per-column nonzeros, ascending k ----------
__global__ __launch_bounds__(256) void compress_kernel(
    const float* __restrict__ W, const float* __restrict__ mask,
    unsigned short* __restrict__ cIdx, float* __restrict__ cVal,
    int* __restrict__ cnt) {
  const int j = blockIdx.x * 4 + (threadIdx.x >> 6);  // one wave per column
  const int lane = threadIdx.x & 63;
  if (j >= N_DIM) return;
  const float* mr = mask + (size_t)j * K_DIM;
  const float* wr = W + (size_t)j * K_DIM;
  int base = 0;
#pragma unroll
  for (int c = 0; c < K_DIM / 64; ++c) {
    const int k = c * 64 + lane;
    const bool act = (mr[k] != 0.0f);
    const unsigned long long bal = __ballot(act);
    const int pos = __popcll(bal & ((1ull << lane) - 1ull));
    if (act && base + pos < MAXE) {
      cIdx[(size_t)j * MAXE + base + pos] = (unsigned short)k;
      cVal[(size_t)j * MAXE + base + pos] = wr[k];   // mask==1 -> exact
    }
    base += (int)__popcll(bal);
  }
  if (lane == 0) cnt[j] = base < MAXE ? base : MAXE;
}

// ---------- counting sort by nnz; per-chunk (64 cols) max count ----------
__global__ __launch_bounds__(256) void sort_kernel(
    const int* __restrict__ cnt, int* __restrict__ perm, int* __restrict__ tEc) {
  __shared__ int hist[MAXE + 1];
  __shared__ int off[MAXE + 1];
  const int tid = threadIdx.x;
  if (tid <= MAXE) hist[tid] = 0;
  __syncthreads();
  for (int j = tid; j < N_DIM; j += 256) atomicAdd(&hist[cnt[j]], 1);
  __syncthreads();
  if (tid == 0) {
    int s = 0;
    for (int c = 0; c <= MAXE; ++c) { off[c] = s; s += hist[c]; }
  }
  __syncthreads();
  for (int j = tid; j < N_DIM; j += 256) {
    const int p = atomicAdd(&off[cnt[j]], 1);
    perm[p] = j;                                   // ascending count
  }
  __syncthreads();
  // chunk c = sorted ranks [c*64, c*64+64); ascending -> max is last
  if (tid < 64) tEc[tid] = cnt[perm[tid * 64 + 63]];
}

// ---------- transposed pairs in sorted order + permuted bias/boost ----------
__global__ __launch_bounds__(256) void fillT_kernel(
    const unsigned short* __restrict__ cIdx, const float* __restrict__ cVal,
    const int* __restrict__ cnt, const int* __restrict__ perm,
    const float* __restrict__ bvec, const float* __restrict__ boost,
    uint2* __restrict__ pairT, float* __restrict__ bperm,
    float* __restrict__ gperm) {
  const int s = blockIdx.x * 256 + threadIdx.x;    // sorted rank 0..4095
  const int j = perm[s];
  const int c = cnt[j];
  bperm[s] = bvec[j];
  gperm[s] = boost[j];
  pairT[(size_t)MAXE * N_DIM + s] = (uint2){0u, 0u};   // prefetch guard row
#pragma unroll 4
  for (int e = 0; e < MAXE; ++e) {
    uint2 pr;
    if (e < c) {
      pr.x = (u32)cIdx[(size_t)j * MAXE + e] * (u32)(XPAD * 4); // LDS byte off
      pr.y = __float_as_uint(cVal[(size_t)j * MAXE + e]);
    } else {
      pr.x = 0u; pr.y = 0u;                        // exact fold no-op
    }
    pairT[(size_t)e * N_DIM + s] = pr;             // coalesced across s
  }
}

// ---------- fold v3: lane=column, imm-offset row sweep ----------
__global__ __launch_bounds__(1024, 1) void fold_kernel(
    const float* __restrict__ x, const uint2* __restrict__ pairT,
    const int* __restrict__ tEc, float* __restrict__ yperm) {
  __shared__ float xT[K_DIM * XPAD];               // 133,120 B -> 1 block/CU
  const int tid = threadIdx.x;
  const int lane = tid & 63;
  const int wave = __builtin_amdgcn_readfirstlane(tid >> 6);  // 0..15
  const int row0 = blockIdx.x * ROWS_A;

  // stage xT[k*65 + r] = x[row0+r][k]; k tid-minor -> coalesced global;
  // LDS write banks (k+r)%32 consecutive -> conflict-free
#pragma unroll 1
  for (int i = 0; i < (ROWS_A * K_DIM) / 1024; ++i) {  // 32 iters
    const int flat = i * 1024 + tid;
    const int r = flat >> 9;                           // /512
    const int k = flat & (K_DIM - 1);
    xT[k * XPAD + r] = x[(size_t)(row0 + r) * K_DIM + k];
  }
  __syncthreads();

  // 64 chunks of 64 sorted columns; wave w takes {w, w+16, w+32, w+48}
  // (one per count-quartile -> balanced wave totals)
#pragma unroll 1
  for (int i = 0; i < 4; ++i) {
    const int c = i * 16 + wave;
    const int E = tEc[c];                          // uniform s_load
    const uint2* pt = pairT + (size_t)c * 64 + lane;
    float acc[64];
#pragma unroll
    for (int r = 0; r < 64; ++r) acc[r] = 0.0f;

    uint2 cur = pt[0];
#pragma unroll 1
    for (int e = 0; e < E; ++e) {
      const uint2 nxt = pt[(size_t)(e + 1) * N_DIM];   // prefetch (guard row)
      const float w = __uint_as_float(cur.y);
      const float* bp = (const float*)((const char*)xT + cur.x);
#pragma unroll
      for (int r = 0; r < 64; ++r)                 // ds_read_b32 offset:4r
        acc[r] = fmaf(w, bp[r], acc[r]);           // ascending-k fold
      cur = nxt;
    }

    // y_perm[row0+r][c*64+lane]: 256B contiguous per r, coalesced
    float* yp = yperm + (size_t)row0 * N_DIM + c * 64 + lane;
#pragma unroll
    for (int r = 0; r < 64; ++r)
      yp[(size_t)r * N_DIM] = acc[r];
  }
}

// ---------- select v4: wave/row, kv-only regs, LDS-parked y ----------
__global__ __launch_bounds__(256) void select_kernel(
    const float* __restrict__ bperm, const float* __restrict__ gperm,
    const int* __restrict__ perm, const int* __restrict__ kptr,
    float* __restrict__ out) {
  __shared__ float yrow[4][N_DIM];                 // 64 KB -> 2 blocks/CU
  const int tid = threadIdx.x;
  const int lane = tid & 63;
  const int wave = tid >> 6;
  const int row = blockIdx.x * 4 + wave;
  const u32 kk = (u32)kptr[0];
  float* orow = out + (size_t)row * N_DIM;

  u32 kv[64];
#pragma unroll
  for (int v = 0; v < 16; ++v) {
    const int j = v * 256 + lane * 4;              // f32x4, coalesced
    const f32x4 a = *(const f32x4*)(orow + j);
    const f32x4 b = *(const f32x4*)(bperm + j);
    const f32x4 g = *(const f32x4*)(gperm + j);
    *(f32x4*)(&yrow[wave][j]) = a;                 // park pristine y
#pragma unroll
    for (int q = 0; q < 4; ++q) {
      const float yy = a[q] + b[q];                // single f32 add
      const u32 u = __float_as_uint(yy * g[q]);    // single f32 mult
      kv[v * 4 + q] = (u & 0x80000000u) ? ~u : (u | 0x80000000u);
    }
  }

  // exact k-th-largest key: P = max C with count(key >= C) >= k (ties >=)
  u32 P = 0u;
#pragma unroll 1
  for (int bit = 31; bit >= 0; --bit) {
    const u32 C = P | (1u << bit);
    u32 cc = 0u;
#pragma unroll
    for (int s = 0; s < 64; ++s)
      cc += (u32)__popcll(__ballot(kv[s] >= C));   // v_cmp + s_bcnt1
    if (cc >= kk) P = C;                           // uniform
  }

  // write phase: recompute yy/key from parked y (bit-identical), scatter to
  // original columns; all reads of orow completed above -> no RAW hazard
#pragma unroll
  for (int v = 0; v < 16; ++v) {
    const int j = v * 256 + lane * 4;
    const int4 pj = *(const int4*)(perm + j);
    const f32x4 b = *(const f32x4*)(bperm + j);
    const f32x4 g = *(const f32x4*)(gperm + j);
    const f32x4 a = *(const f32x4*)(&yrow[wave][j]);
#pragma unroll
    for (int q = 0; q < 4; ++q) {
      const float yy = a[q] + b[q];
      const u32 u = __float_as_uint(yy * g[q]);
      const u32 key = (u & 0x80000000u) ? ~u : (u | 0x80000000u);
      const int col = (&pj.x)[q];
      orow[col] = (key >= P) ? yy : 0.0f;          // L2 write-combined
    }
  }
}

extern "C" void kernel_launch(void* const* d_in, const int* in_sizes, int n_in,
                              void* d_out, int out_size, void* d_ws, size_t ws_size,
                              hipStream_t stream) {
  const float* x     = (const float*)d_in[0];
  const float* W     = (const float*)d_in[1];
  const float* bvec  = (const float*)d_in[2];
  const float* wmask = (const float*)d_in[3];
  const float* duty  = (const float*)d_in[4];
  const int* kptr    = (const int*)d_in[5];
  float* out = (float*)d_out;

  uint8_t* ws = (uint8_t*)d_ws;
  unsigned short* cIdx = (unsigned short*)(ws);                 // 512 KiB
  float* cVal          = (float*)(ws + (1u << 20));             // 1 MiB
  int* cnt             = (int*)(ws + (2u << 20));               // 16 KiB
  float* boost         = (float*)(ws + (2u << 20) + (64u << 10));
  int* perm            = (int*)(ws + (2u << 20) + (128u << 10)); // 16 KiB
  int* tEc             = (int*)(ws + (2u << 20) + (192u << 10)); // 256 B
  float* bperm         = (float*)(ws + (2u << 20) + (256u << 10));
  float* gperm         = (float*)(ws + (2u << 20) + (320u << 10));
  uint2* pairT         = (uint2*)(ws + (4u << 20));             // 2.08 MiB

  boost_kernel<<<16, 256, 0, stream>>>(duty, kptr, boost);
  compress_kernel<<<N_DIM / 4, 256, 0, stream>>>(W, wmask, cIdx, cVal, cnt);
  sort_kernel<<<1, 256, 0, stream>>>(cnt, perm, tEc);
  fillT_kernel<<<N_DIM / 256, 256, 0, stream>>>(cIdx, cVal, cnt, perm, bvec,
                                                boost, pairT, bperm, gperm);
  fold_kernel<<<BATCH / ROWS_A, 1024, 0, stream>>>(x, pairT, tEc, out);
  select_kernel<<<BATCH / 4, 256, 0, stream>>>(bperm, gperm, perm, kptr, out);
}

// Round 10
// 1040.176 us; speedup vs baseline: 1.0888x; 1.0808x over previous
//
#include <hip/hip_runtime.h>
#include <stdint.h>
#include <math.h>

// Round 16 = round 15 resubmitted verbatim (container failed twice; kernel
// never executed — no dispatch, no absmax; bounds re-audited, graph-capture
// safe). Theory recap:
// r10's 336us fold == DS-pipe throughput cap (123K ds_read_b32/CU x 5.8cyc
// = 298us). Any LDS-b32 gather is capped ~300us. Fix: gather from GLOBAL
// xTg[k][row] — 64 lanes x 4B contiguous = 256B coalesced load, L2-served
// (per-XCD x slices ~4MB; all of xTg 32MB fits L3). ~4GB / 34.5TB/s ~117us.
//  - transpose kernel: x[16384][512] -> xTg[512][16384] (LDS 64x65 tile).
//  - fold_g: batched in-order VMEM pair stream + readlane broadcast,
//    gather via global load; no LDS tile, no barrier.
//  - pairs carry RAW k (global path <<14, LDS fallback *260).
//  - ws_size guard: xTg needs 42MB; else fall back to r13 LDS fold.
//  - select v5: contiguous in-place f32x4 read -> ballot bit-search ->
//    re-read -> recompute -> store; no LDS, ~90 VGPR.
// Numerics unchanged (validated): ascending-k f32 fmaf fold from +0
// (zero-pad exact no-op), +bias, *boost, monotone-u32 key, ties >=.

#define BATCH 16384
#define K_DIM 512
#define N_DIM 4096
#define MAXE 64
#define ROWS_A 64
#define XPAD 65   // LDS-fallback xT k-stride floats

typedef float f32x4 __attribute__((ext_vector_type(4)));
typedef unsigned int u32;

#define RDL(v, l) __builtin_amdgcn_readlane((int)(v), (l))

// ---------- boost table ----------
__global__ void boost_kernel(const float* __restrict__ duty,
                             const int* __restrict__ kptr,
                             float* __restrict__ boost) {
  const int j = blockIdx.x * blockDim.x + threadIdx.x;
  if (j < N_DIM) {
    const float td = (float)((double)kptr[0] / (double)N_DIM);
    const float arg = 0.5f * (td - duty[j]);      // f32 ops, as reference
    boost[j] = (float)exp((double)arg);           // correctly-rounded f32 exp
  }
}

// ---------- compress: per-column nonzeros, ascending k ----------
__global__ __launch_bounds__(256) void compress_kernel(
    const float* __restrict__ W, const float* __restrict__ mask,
    unsigned short* __restrict__ cIdx, float* __restrict__ cVal,
    int* __restrict__ cnt) {
  const int j = blockIdx.x * 4 + (threadIdx.x >> 6);  // one wave per column
  const int lane = threadIdx.x & 63;
  if (j >= N_DIM) return;
  const float* mr = mask + (size_t)j * K_DIM;
  const float* wr = W + (size_t)j * K_DIM;
  int base = 0;
#pragma unroll
  for (int c = 0; c < K_DIM / 64; ++c) {
    const int k = c * 64 + lane;
    const bool act = (mr[k] != 0.0f);
    const unsigned long long bal = __ballot(act);
    const int pos = __popcll(bal & ((1ull << lane) - 1ull));
    if (act && base + pos < MAXE) {
      cIdx[(size_t)j * MAXE + base + pos] = (unsigned short)k;
      cVal[(size_t)j * MAXE + base + pos] = wr[k];   // mask==1 -> exact
    }
    base += (int)__popcll(bal);
  }
  if (lane == 0) cnt[j] = base < MAXE ? base : MAXE;
}

// ---------- per-4-col max count, rounded up to 4 ----------
__global__ __launch_bounds__(256) void cmax_kernel(
    const int* __restrict__ cnt, int* __restrict__ cm4) {
  const int i = blockIdx.x * 256 + threadIdx.x;    // 0..1023
  const int4 c = *(const int4*)(cnt + i * 4);
  int m = c.x > c.y ? c.x : c.y;
  m = c.z > m ? c.z : m;
  m = c.w > m ? c.w : m;
  cm4[i] = (m + 3) & ~3;
}

// ---------- pack (k, w-bits) pairs, zero-padded to MAXE ----------
__global__ __launch_bounds__(256) void fillA_kernel(
    const unsigned short* __restrict__ cIdx, const float* __restrict__ cVal,
    const int* __restrict__ cnt, uint2* __restrict__ pairsA) {
  const int idx = blockIdx.x * 256 + threadIdx.x;  // 0 .. 4096*64-1
  const int j = idx >> 6;
  const int e = idx & 63;
  uint2 pr;
  if (e < cnt[j]) {
    pr.x = (u32)cIdx[(size_t)j * MAXE + e];        // RAW k
    pr.y = __float_as_uint(cVal[(size_t)j * MAXE + e]);
  } else {
    pr.x = 0u; pr.y = 0u;                          // exact fold no-op
  }
  pairsA[idx] = pr;
}

// ---------- transpose: x[B][K] -> xTg[K][B] ----------
__global__ __launch_bounds__(256) void transpose_kernel(
    const float* __restrict__ x, float* __restrict__ xTg) {
  __shared__ float t[64][65];
  const int lane = threadIdx.x & 63;
  const int quad = threadIdx.x >> 6;               // 0..3
  const int kb = (blockIdx.x & 7) * 64;            // 8 k-tiles
  const int rb = (blockIdx.x >> 3) * 64;           // 256 row-tiles
#pragma unroll
  for (int i = 0; i < 16; ++i) {
    const int r = quad * 16 + i;
    t[lane][r] = x[(size_t)(rb + r) * K_DIM + kb + lane];  // coalesced read
  }
  __syncthreads();
#pragma unroll
  for (int i = 0; i < 16; ++i) {
    const int kq = quad * 16 + i;
    xTg[(size_t)(kb + kq) * BATCH + rb + lane] = t[kq][lane]; // coalesced write
  }
}

// ---------- fold v5: lane=row, global-gather from xTg, no LDS ----------
__global__ __launch_bounds__(1024, 1) void fold_g_kernel(
    const float* __restrict__ xTg, const uint2* __restrict__ pairsA,
    const int* __restrict__ cm4, float* __restrict__ y) {
  const int tid = threadIdx.x;
  const int lane = tid & 63;
  const int wave = __builtin_amdgcn_readfirstlane(tid >> 6);  // 0..15
  const int row0 = blockIdx.x * ROWS_A;
  const float* xb = xTg + row0;                    // + (k<<14) + lane

  const int jbase = wave * 256;                    // 256 cols per wave
  const int cmv = cm4[(jbase >> 2) + lane];        // lane s: subgroup s bound

#pragma unroll 1
  for (int g = 0; g < 8; ++g) {                    // 8 groups of 32 cols
    float acc[32];
#pragma unroll
    for (int q = 0; q < 32; ++q) acc[q] = 0.0f;

#pragma unroll
    for (int h = 0; h < 2; ++h) {                  // 2 halves x 4 subgroups
      // batched VMEM: 16 coalesced dwordx2 pair loads (in-order, counted)
      uint2 ev[4][4];
#pragma unroll
      for (int c4 = 0; c4 < 4; ++c4)
#pragma unroll
        for (int cc = 0; cc < 4; ++cc)
          ev[c4][cc] =
              pairsA[(size_t)(jbase + g * 32 + h * 16 + c4 * 4 + cc) * MAXE +
                     lane];                        // lane = entry index

#pragma unroll
      for (int c4 = 0; c4 < 4; ++c4) {
        const int sg = g * 8 + h * 4 + c4;         // uniform
        const int cmax = RDL(cmv, sg);             // multiple of 4
        float a0 = 0.0f, a1 = 0.0f, a2 = 0.0f, a3 = 0.0f;
#pragma unroll 1
        for (int e = 0; e < cmax; e += 4) {
#pragma unroll
          for (int q = 0; q < 4; ++q) {            // 16 gathers in flight
            const u32 k0 = (u32)RDL(ev[c4][0].x, e + q) << 14;  // *16384
            const u32 k1 = (u32)RDL(ev[c4][1].x, e + q) << 14;
            const u32 k2 = (u32)RDL(ev[c4][2].x, e + q) << 14;
            const u32 k3 = (u32)RDL(ev[c4][3].x, e + q) << 14;
            const float x0 = xb[k0 + lane];        // 256B coalesced, L2-hot
            const float x1 = xb[k1 + lane];
            const float x2 = xb[k2 + lane];
            const float x3 = xb[k3 + lane];
            const float w0 = __uint_as_float((u32)RDL(ev[c4][0].y, e + q));
            const float w1 = __uint_as_float((u32)RDL(ev[c4][1].y, e + q));
            const float w2 = __uint_as_float((u32)RDL(ev[c4][2].y, e + q));
            const float w3 = __uint_as_float((u32)RDL(ev[c4][3].y, e + q));
            a0 = fmaf(w0, x0, a0);                 // ascending-k fold
            a1 = fmaf(w1, x1, a1);
            a2 = fmaf(w2, x2, a2);
            a3 = fmaf(w3, x3, a3);
          }
        }
        acc[h * 16 + c4 * 4 + 0] = a0;
        acc[h * 16 + c4 * 4 + 1] = a1;
        acc[h * 16 + c4 * 4 + 2] = a2;
        acc[h * 16 + c4 * 4 + 3] = a3;
      }
    }

    // 128B contiguous per lane (= per row) -> full HBM granules
    float* yp = y + (size_t)(row0 + lane) * N_DIM + jbase + g * 32;
#pragma unroll
    for (int q = 0; q < 8; ++q)
      *(f32x4*)(yp + q * 4) =
          (f32x4){acc[q * 4], acc[q * 4 + 1], acc[q * 4 + 2], acc[q * 4 + 3]};
  }
}

// ---------- fold fallback (r13): LDS tile + ds_read_b32 gather ----------
__global__ __launch_bounds__(1024, 1) void fold_lds_kernel(
    const float* __restrict__ x, const uint2* __restrict__ pairsA,
    const int* __restrict__ cm4, float* __restrict__ y) {
  __shared__ float xT[K_DIM * XPAD];               // 133,120 B
  const int tid = threadIdx.x;
  const int lane = tid & 63;
  const int wave = __builtin_amdgcn_readfirstlane(tid >> 6);
  const int row0 = blockIdx.x * ROWS_A;
#pragma unroll 1
  for (int i = 0; i < (ROWS_A * K_DIM) / 1024; ++i) {
    const int flat = i * 1024 + tid;
    const int r = flat >> 9;
    const int k = flat & (K_DIM - 1);
    xT[k * XPAD + r] = x[(size_t)(row0 + r) * K_DIM + k];
  }
  const int jbase = wave * 256;
  const int cmv = cm4[(jbase >> 2) + lane];
  const int vl4 = lane * 4;
  __syncthreads();
#pragma unroll 1
  for (int g = 0; g < 8; ++g) {
    float acc[32];
#pragma unroll
    for (int q = 0; q < 32; ++q) acc[q] = 0.0f;
#pragma unroll
    for (int h = 0; h < 2; ++h) {
      uint2 ev[4][4];
#pragma unroll
      for (int c4 = 0; c4 < 4; ++c4)
#pragma unroll
        for (int cc = 0; cc < 4; ++cc)
          ev[c4][cc] =
              pairsA[(size_t)(jbase + g * 32 + h * 16 + c4 * 4 + cc) * MAXE +
                     lane];
#pragma unroll
      for (int c4 = 0; c4 < 4; ++c4) {
        const int sg = g * 8 + h * 4 + c4;
        const int cmax = RDL(cmv, sg);
        float a0 = 0.0f, a1 = 0.0f, a2 = 0.0f, a3 = 0.0f;
#pragma unroll 1
        for (int e = 0; e < cmax; e += 4) {
#pragma unroll
          for (int q = 0; q < 4; ++q) {
            const int s0 = RDL(ev[c4][0].x, e + q) * (XPAD * 4);
            const int s1 = RDL(ev[c4][1].x, e + q) * (XPAD * 4);
            const int s2 = RDL(ev[c4][2].x, e + q) * (XPAD * 4);
            const int s3 = RDL(ev[c4][3].x, e + q) * (XPAD * 4);
            const float w0 = __uint_as_float((u32)RDL(ev[c4][0].y, e + q));
            const float w1 = __uint_as_float((u32)RDL(ev[c4][1].y, e + q));
            const float w2 = __uint_as_float((u32)RDL(ev[c4][2].y, e + q));
            const float w3 = __uint_as_float((u32)RDL(ev[c4][3].y, e + q));
            a0 = fmaf(w0, *(const float*)((const char*)xT + (s0 + vl4)), a0);
            a1 = fmaf(w1, *(const float*)((const char*)xT + (s1 + vl4)), a1);
            a2 = fmaf(w2, *(const float*)((const char*)xT + (s2 + vl4)), a2);
            a3 = fmaf(w3, *(const float*)((const char*)xT + (s3 + vl4)), a3);
          }
        }
        acc[h * 16 + c4 * 4 + 0] = a0;
        acc[h * 16 + c4 * 4 + 1] = a1;
        acc[h * 16 + c4 * 4 + 2] = a2;
        acc[h * 16 + c4 * 4 + 3] = a3;
      }
    }
    float* yp = y + (size_t)(row0 + lane) * N_DIM + jbase + g * 32;
#pragma unroll
    for (int q = 0; q < 8; ++q)
      *(f32x4*)(yp + q * 4) =
          (f32x4){acc[q * 4], acc[q * 4 + 1], acc[q * 4 + 2], acc[q * 4 + 3]};
  }
}

// ---------- select v5: contiguous in-place, ballot bit-search, no LDS ----------
__global__ __launch_bounds__(256) void select_kernel(
    const float* __restrict__ bvec, const float* __restrict__ boost,
    const int* __restrict__ kptr, float* __restrict__ out) {
  const int lane = threadIdx.x & 63;
  const int row = blockIdx.x * 4 + (threadIdx.x >> 6);
  const u32 kk = (u32)kptr[0];
  float* orow = out + (size_t)row * N_DIM;

  u32 kv[64];
#pragma unroll
  for (int v = 0; v < 16; ++v) {
    const int j = v * 256 + lane * 4;              // f32x4, coalesced
    const f32x4 a = *(const f32x4*)(orow + j);
    const f32x4 b = *(const f32x4*)(bvec + j);
    const f32x4 gv = *(const f32x4*)(boost + j);
#pragma unroll
    for (int q = 0; q < 4; ++q) {
      const float yy = a[q] + b[q];                // single f32 add
      const u32 u = __float_as_uint(yy * gv[q]);   // single f32 mult
      kv[v * 4 + q] = (u & 0x80000000u) ? ~u : (u | 0x80000000u);
    }
  }

  // exact k-th-largest key: P = max C with count(key >= C) >= k (ties >=)
  u32 P = 0u;
#pragma unroll 1
  for (int bit = 31; bit >= 0; --bit) {
    const u32 C = P | (1u << bit);
    u32 cc = 0u;
#pragma unroll
    for (int s = 0; s < 64; ++s)
      cc += (u32)__popcll(__ballot(kv[s] >= C));   // v_cmp + s_bcnt1
    if (cc >= kk) P = C;                           // uniform
  }

  // re-read (L2/L3-hot), recompute bit-identically, contiguous store
#pragma unroll
  for (int v = 0; v < 16; ++v) {
    const int j = v * 256 + lane * 4;
    const f32x4 a = *(const f32x4*)(orow + j);
    const f32x4 b = *(const f32x4*)(bvec + j);
    const f32x4 gv = *(const f32x4*)(boost + j);
    f32x4 o;
#pragma unroll
    for (int q = 0; q < 4; ++q) {
      const float yy = a[q] + b[q];
      const u32 u = __float_as_uint(yy * gv[q]);
      const u32 key = (u & 0x80000000u) ? ~u : (u | 0x80000000u);
      o[q] = (key >= P) ? yy : 0.0f;
    }
    *(f32x4*)(orow + j) = o;
  }
}

extern "C" void kernel_launch(void* const* d_in, const int* in_sizes, int n_in,
                              void* d_out, int out_size, void* d_ws, size_t ws_size,
                              hipStream_t stream) {
  const float* x     = (const float*)d_in[0];
  const float* W     = (const float*)d_in[1];
  const float* bvec  = (const float*)d_in[2];
  const float* wmask = (const float*)d_in[3];
  const float* duty  = (const float*)d_in[4];
  const int* kptr    = (const int*)d_in[5];
  float* out = (float*)d_out;

  uint8_t* ws = (uint8_t*)d_ws;
  unsigned short* cIdx = (unsigned short*)(ws);                 // 512 KiB
  float* cVal          = (float*)(ws + (1u << 20));             // 1 MiB
  int* cnt             = (int*)(ws + (2u << 20));               // 16 KiB
  float* boost         = (float*)(ws + (2u << 20) + (64u << 10));
  int* cm4             = (int*)(ws + (2u << 20) + (128u << 10)); // 4 KiB
  uint2* pairsA        = (uint2*)(ws + (4u << 20));             // 2 MiB
  float* xTg           = (float*)(ws + (8u << 20));             // 33.6 MiB
  const size_t need_xtg = (8u << 20) + (size_t)K_DIM * BATCH * 4;

  boost_kernel<<<16, 256, 0, stream>>>(duty, kptr, boost);
  compress_kernel<<<N_DIM / 4, 256, 0, stream>>>(W, wmask, cIdx, cVal, cnt);
  cmax_kernel<<<4, 256, 0, stream>>>(cnt, cm4);
  fillA_kernel<<<(N_DIM * MAXE) / 256, 256, 0, stream>>>(cIdx, cVal, cnt, pairsA);
  if (ws_size >= need_xtg) {
    transpose_kernel<<<2048, 256, 0, stream>>>(x, xTg);
    fold_g_kernel<<<BATCH / ROWS_A, 1024, 0, stream>>>(xTg, pairsA, cm4, out);
  } else {
    fold_lds_kernel<<<BATCH / ROWS_A, 1024, 0, stream>>>(x, pairsA, cm4, out);
  }
  select_kernel<<<BATCH / 4, 256, 0, stream>>>(bvec, boost, kptr, out);
}